// Round 8
// baseline (262.693 us; speedup 1.0000x reference)
//
#include <hip/hip_runtime.h>

// MultiHeadAttention: B=2, S=2048, D=1024, H=16, DK=64, causal.
// Inputs fp32, output fp32, intermediates bf16.
// R18: flash11 — load-balanced flash. Diagnosis: 2048x128 grid = ALL blocks
//   resident at t=0 (8/CU), no backfill; per-block work varies 32:1 (causal)
//   -> occupancy decays 4->0 waves/SIMD (avg 1.55, 19.4%); lone waves are
//   pure serial latency, which is why VALU-cut/pipeline/setprio were all null.
//   Fix: 1024 blocks x 4 waves, each block = complementary tile pair
//   (q32=63-pr then q32=pr): per-block work uniform ~33-34 steps. Within a
//   tile, 4 waves split steps round-robin; one tile live at a time (VGPR flat).
//   4 blk/CU x 4 waves = 16 waves/CU SUSTAINED. Combine: 2-round LDS tree x2.
// gemms/prep unchanged from R17 (counted-vmcnt 3-buf pipeline, merged prep).
// ws (56 MB, aliased): Wt 8 | Qp 8 | Kp 8 | Vt 8 | Xb 24 (Ap aliases Xb[0:8])

typedef short v8s  __attribute__((ext_vector_type(8)));
typedef short v4ss __attribute__((ext_vector_type(4)));
typedef float v4f  __attribute__((ext_vector_type(4)));
typedef unsigned int v2u __attribute__((ext_vector_type(2)));

#define S_LEN 2048
#define D_DIM 1024
#define NHEAD 16
#define DK 64
#define M_ROWS 4096

__device__ inline unsigned short f2bf(float f) {
    unsigned x;
    __builtin_memcpy(&x, &f, 4);
    unsigned r = x + 0x7fffu + ((x >> 16) & 1u);  // RNE
    return (unsigned short)(r >> 16);
}

// v_cvt_pk_bf16_f32: D.lo = bf16(lo), D.hi = bf16(hi), RNE
__device__ inline unsigned cvtpk_bf16(float lo, float hi) {
    unsigned d;
    asm("v_cvt_pk_bf16_f32 %0, %1, %2" : "=v"(d) : "v"(lo), "v"(hi));
    return d;
}

__device__ inline void gload_lds16(const void* g, void* l) {
    __builtin_amdgcn_global_load_lds(
        (const __attribute__((address_space(1))) unsigned int*)g,
        (__attribute__((address_space(3))) unsigned int*)l, 16, 0, 0);
}

// ---------------------------------------------------------------------------
// prep: fp32->bf16 cvt of q,k,v into Xb[3][4096][1024] (blocks 0..6143)
//       + weight transpose W fp32 [k][n] -> Wt bf16 [n][k] (blocks 6144..7167).
// ---------------------------------------------------------------------------
__global__ __launch_bounds__(256) void prep(
    const float* __restrict__ q, const float* __restrict__ k,
    const float* __restrict__ v,
    const float* __restrict__ W0, const float* __restrict__ W1,
    const float* __restrict__ W2, const float* __restrict__ W3,
    unsigned short* __restrict__ Xb, unsigned short* __restrict__ Wt)
{
    __shared__ unsigned short t[64][72];
    const int id = blockIdx.x;

    if (id < 6144) {
        const int z = id >> 11;
        const int x = id & 2047;
        const float* X = (z == 0) ? q : (z == 1) ? k : v;
        const size_t off = ((size_t)x * 256 + threadIdx.x) * 8;
        float4 f0 = *(const float4*)(X + off);
        float4 f1 = *(const float4*)(X + off + 4);
        v8s p;
        p[0]=(short)f2bf(f0.x); p[1]=(short)f2bf(f0.y); p[2]=(short)f2bf(f0.z); p[3]=(short)f2bf(f0.w);
        p[4]=(short)f2bf(f1.x); p[5]=(short)f2bf(f1.y); p[6]=(short)f2bf(f1.z); p[7]=(short)f2bf(f1.w);
        *(v8s*)(Xb + (size_t)z * M_ROWS * D_DIM + off) = p;
        return;
    }

    const int tt = id - 6144;          // 0..1023
    const int z  = tt >> 8;            // 0..3
    const int rem = tt & 255;
    const int bx = rem & 15;
    const int by = rem >> 4;
    const float* W = (z == 0) ? W0 : (z == 1) ? W1 : (z == 2) ? W2 : W3;
    unsigned short* dst = Wt + (size_t)z * D_DIM * D_DIM;

    const int n0 = bx * 64, k0 = by * 64;
    const int tid = threadIdx.x;
    const int lr = tid >> 4;
    const int lc = (tid & 15) * 4;

#pragma unroll
    for (int kk = 0; kk < 64; kk += 16) {
        float4 f = *(const float4*)(W + (size_t)(k0 + kk + lr) * D_DIM + n0 + lc);
        t[lc + 0][kk + lr] = f2bf(f.x);
        t[lc + 1][kk + lr] = f2bf(f.y);
        t[lc + 2][kk + lr] = f2bf(f.z);
        t[lc + 3][kk + lr] = f2bf(f.w);
    }
    __syncthreads();
    const int wr = tid >> 2;
    const int wc = (tid & 3) * 16;
    v8s o0, o1;
#pragma unroll
    for (int e = 0; e < 8; e++) { o0[e] = t[wr][wc + e]; o1[e] = t[wr][wc + 8 + e]; }
    *(v8s*)(dst + (size_t)(n0 + wr) * D_DIM + k0 + wc)     = o0;
    *(v8s*)(dst + (size_t)(n0 + wr) * D_DIM + k0 + wc + 8) = o1;
}

// ---------------------------------------------------------------------------
// Fused QKV projection — counted-vmcnt 3-buffer pipeline (R17, unchanged).
// ---------------------------------------------------------------------------
__global__ __launch_bounds__(256) void gemm_qkv(
    const unsigned short* __restrict__ Xb,
    const unsigned short* __restrict__ Wt,
    const float* __restrict__ bq, const float* __restrict__ bk,
    const float* __restrict__ bv,
    unsigned short* __restrict__ Qp, unsigned short* __restrict__ Kp,
    unsigned short* __restrict__ Vt)
{
    const int id   = blockIdx.x;
    const int xcd  = id & 7;
    const int slot = id >> 3;          // 0..95
    const int nblk = slot & 7;
    const int mg   = (slot >> 3) & 3;
    const int z    = slot >> 5;        // 0..2
    const int mblk = mg * 8 + xcd;     // 0..31

    const unsigned short* X = Xb + (size_t)z * M_ROWS * D_DIM;
    const unsigned short* W = Wt + (size_t)z * D_DIM * D_DIM;
    const float* bias = (z == 0) ? bq : (z == 1) ? bk : bv;

    __shared__ unsigned short lds_a[3][128 * 32];   // 3 x 8 KB
    __shared__ unsigned short lds_b[3][128 * 32];   // 3 x 8 KB

    const int tid  = threadIdx.x;
    const int lane = tid & 63;
    const int wave = tid >> 6;
    const int wm   = wave >> 1;
    const int wn   = wave & 1;
    const int quad = lane >> 4;
    const int col  = lane & 15;
    const int m0   = mblk * 128;
    const int n0   = nblk * 128;

    v4f acc[4][4];
#pragma unroll
    for (int i = 0; i < 4; i++)
#pragma unroll
        for (int j = 0; j < 4; j++)
#pragma unroll
            for (int r = 0; r < 4; r++) acc[i][j][r] = 0.0f;

    const int srow = wave * 16 + (lane >> 2);
    const int schk = (lane & 3) * 8;
    const int soff = wave * 512 + lane * 8;

    const unsigned short* Xr0 = X + (size_t)(m0 + srow) * D_DIM + schk;
    const unsigned short* Xr1 = X + (size_t)(m0 + 64 + srow) * D_DIM + schk;
    const unsigned short* Wr0 = W + (size_t)(n0 + srow) * D_DIM + schk;
    const unsigned short* Wr1 = W + (size_t)(n0 + 64 + srow) * D_DIM + schk;

    auto stage = [&](unsigned short* A, unsigned short* B, int k0) {
        gload_lds16(Xr0 + k0, A + soff);
        gload_lds16(Xr1 + k0, A + soff + 2048);
        gload_lds16(Wr0 + k0, B + soff);
        gload_lds16(Wr1 + k0, B + soff + 2048);
    };

    auto compute = [&](const unsigned short* A, const unsigned short* B) {
        v8s af[4], bf[4];
#pragma unroll
        for (int mt = 0; mt < 4; mt++)
            af[mt] = *(const v8s*)(A + (wm * 64 + mt * 16 + col) * 32 + quad * 8);
#pragma unroll
        for (int nt = 0; nt < 4; nt++)
            bf[nt] = *(const v8s*)(B + (wn * 64 + nt * 16 + col) * 32 + quad * 8);
#pragma unroll
        for (int mt = 0; mt < 4; mt++)
#pragma unroll
            for (int nt = 0; nt < 4; nt++)
                acc[mt][nt] = __builtin_amdgcn_mfma_f32_16x16x32_bf16(
                    af[mt], bf[nt], acc[mt][nt], 0, 0, 0);
    };

    stage(lds_a[0], lds_b[0], 0);
    stage(lds_a[1], lds_b[1], 32);

    unsigned short *ra = lds_a[0], *rb = lds_b[0];
    unsigned short *pa = lds_a[1], *pb = lds_b[1];
    unsigned short *sa = lds_a[2], *sb = lds_b[2];

    for (int k0 = 0; k0 < 992; k0 += 32) {      // steps 0..30
        asm volatile("s_waitcnt vmcnt(4)" ::: "memory");
        asm volatile("s_waitcnt lgkmcnt(0)" ::: "memory");
        __builtin_amdgcn_sched_barrier(0);
        __builtin_amdgcn_s_barrier();
        __builtin_amdgcn_sched_barrier(0);
        if (k0 + 64 < 1024) stage(sa, sb, k0 + 64);
        compute(ra, rb);
        unsigned short* t;
        t = ra; ra = pa; pa = sa; sa = t;
        t = rb; rb = pb; pb = sb; sb = t;
    }
    asm volatile("s_waitcnt vmcnt(0)" ::: "memory");
    asm volatile("s_waitcnt lgkmcnt(0)" ::: "memory");
    __builtin_amdgcn_sched_barrier(0);
    __builtin_amdgcn_s_barrier();
    __builtin_amdgcn_sched_barrier(0);
    compute(ra, rb);

    int   nn[4];
    float bvv[4];
#pragma unroll
    for (int nt = 0; nt < 4; nt++) {
        nn[nt]  = n0 + wn * 64 + nt * 16 + col;
        bvv[nt] = bias[nn[nt]];
    }

    if (z < 2) {
        unsigned short* out = (z == 0) ? Qp : Kp;
#pragma unroll
        for (int mt = 0; mt < 4; mt++) {
#pragma unroll
            for (int nt = 0; nt < 4; nt++) {
                const int h  = nn[nt] >> 6;
                const int dk = nn[nt] & 63;
#pragma unroll
                for (int r = 0; r < 4; r++) {
                    int row = m0 + wm * 64 + mt * 16 + quad * 4 + r;
                    int b   = row >> 11, t = row & 2047;
                    out[(((size_t)(b * NHEAD + h) * S_LEN) + t) * DK + dk] =
                        f2bf(acc[mt][nt][r] + bvv[nt]);
                }
            }
        }
    } else {
#pragma unroll
        for (int mt = 0; mt < 4; mt++) {
#pragma unroll
            for (int nt = 0; nt < 4; nt++) {
                const int h  = nn[nt] >> 6;
                const int dk = nn[nt] & 63;
                int row = m0 + wm * 64 + mt * 16 + quad * 4;
                int b   = row >> 11, t = row & 2047;
                v4ss pk;
#pragma unroll
                for (int r = 0; r < 4; r++) pk[r] = (short)f2bf(acc[mt][nt][r] + bvv[nt]);
                *(v4ss*)(Vt + ((size_t)(b * NHEAD + h) * DK + dk) * S_LEN + t) = pk;
            }
        }
    }
}

// ---------------------------------------------------------------------------
// Flash attention v11 — load-balanced: 1024 blocks x 4 waves, each block does
// complementary q-tile pair (63-pr, pr) of one bh; waves split a tile's KV
// steps round-robin (step = wave, wave+4, ...). One tile live at a time.
// Swapped QK^T P-pack; fixed-CM deferred softmax; 2-round combine tree.
// ---------------------------------------------------------------------------
__global__ __launch_bounds__(256) void flash11(
    const unsigned short* __restrict__ Qp,
    const unsigned short* __restrict__ Kp,
    const unsigned short* __restrict__ Vt,
    unsigned short* __restrict__ Op)
{
    // pw: 4 waves x [32][72] shorts = 18432 B | combine 2 x 64x34 f32 = 17408 B
    __shared__ __align__(16) unsigned char smem[18432];

    const int tid  = threadIdx.x;
    const int wave = tid >> 6;
    const int lane = tid & 63;
    const int quad = lane >> 4;
    const int col  = lane & 15;

    unsigned short* pw = (unsigned short*)smem + wave * (32 * 72);

    const int i   = blockIdx.x;
    const int xcd = i & 7;
    const int j   = i >> 3;            // 0..127
    const int bh  = xcd * 4 + (j & 3);
    const int pr  = j >> 2;            // 0..31

    const unsigned short* Qh = Qp + (size_t)bh * S_LEN * DK;
    const unsigned short* Kh = Kp + (size_t)bh * S_LEN * DK;
    const unsigned short* Vh = Vt + (size_t)bh * DK * S_LEN;

    const float CS = 0.18033688f;   // 0.125*log2(e)
    const float CM = 28.8539008f;   // 20*log2(e)

    float* cb0 = (float*)smem;
    float* cb1 = cb0 + 64 * 34;

    auto process = [&](int q32) {
        const int r0 = q32 * 32;
        const int nsteps = (q32 >> 1) + 1;

        v8s qf[2][2];
#pragma unroll
        for (int mt = 0; mt < 2; mt++)
#pragma unroll
            for (int c = 0; c < 2; c++)
                qf[mt][c] = *(const v8s*)(Qh + (size_t)(r0 + mt * 16 + col) * DK + c * 32 + quad * 8);

        float lpart[2] = {0.f, 0.f};
        v4f acc_o[2][4];
#pragma unroll
        for (int mt = 0; mt < 2; mt++)
#pragma unroll
            for (int nt = 0; nt < 4; nt++)
#pragma unroll
                for (int r = 0; r < 4; r++) acc_o[mt][nt][r] = 0.0f;

        // preload K for this wave's first step (kv = wave*64 <= 192 < 2048 ok)
        v8s kc[2][4];
        const int kvp = wave * 64;
#pragma unroll
        for (int c = 0; c < 2; c++)
#pragma unroll
            for (int nt = 0; nt < 4; nt++)
                kc[c][nt] = *(const v8s*)(Kh + (size_t)(kvp + nt * 16 + col) * DK + c * 32 + quad * 8);

        for (int step = wave; step < nsteps; step += 4) {
            const int kv0 = step * 64;
            const int kvn = (step + 4 < nsteps) ? kv0 + 256 : kv0;

            v8s vf[2][4];
#pragma unroll
            for (int c = 0; c < 2; c++)
#pragma unroll
                for (int nt = 0; nt < 4; nt++)
                    vf[c][nt] = *(const v8s*)(Vh + (size_t)(nt * 16 + col) * S_LEN + kv0 + c * 32 + quad * 8);
            v8s kn[2][4];
#pragma unroll
            for (int c = 0; c < 2; c++)
#pragma unroll
                for (int nt = 0; nt < 4; nt++)
                    kn[c][nt] = *(const v8s*)(Kh + (size_t)(kvn + nt * 16 + col) * DK + c * 32 + quad * 8);

#pragma unroll
            for (int mt = 0; mt < 2; mt++) {
                // SWAPPED operands: lane holds q=col, kv = nt*16 + quad*4 + r
                v4f s[4];
                __builtin_amdgcn_s_setprio(1);
#pragma unroll
                for (int nt = 0; nt < 4; nt++) {
#pragma unroll
                    for (int r = 0; r < 4; r++) s[nt][r] = 0.0f;
#pragma unroll
                    for (int c = 0; c < 2; c++)
                        s[nt] = __builtin_amdgcn_mfma_f32_16x16x32_bf16(kc[c][nt], qf[mt][c], s[nt], 0, 0, 0);
                }
                __builtin_amdgcn_s_setprio(0);

                const int rbase = r0 + mt * 16;
                float lp = 0.f;
                if (kv0 + 64 > rbase) {
#pragma unroll
                    for (int nt = 0; nt < 4; nt++) {
#pragma unroll
                        for (int r = 0; r < 4; r++) {
                            float p = __builtin_amdgcn_exp2f(fmaf(s[nt][r], CS, -CM));
                            if (kv0 + nt * 16 + quad * 4 + r > rbase + col) p = 0.0f;
                            s[nt][r] = p;
                            lp += p;
                        }
                    }
                } else {
#pragma unroll
                    for (int nt = 0; nt < 4; nt++) {
#pragma unroll
                        for (int r = 0; r < 4; r++) {
                            float p = __builtin_amdgcn_exp2f(fmaf(s[nt][r], CS, -CM));
                            s[nt][r] = p;
                            lp += p;
                        }
                    }
                }
                lpart[mt] += lp;

#pragma unroll
                for (int nt = 0; nt < 4; nt++) {
                    unsigned u0 = cvtpk_bf16(s[nt][0], s[nt][1]);
                    unsigned u1 = cvtpk_bf16(s[nt][2], s[nt][3]);
                    v2u w; w[0] = u0; w[1] = u1;
                    *(v2u*)(pw + (mt * 16 + col) * 72 + nt * 16 + quad * 4) = w;
                }
            }

            __builtin_amdgcn_s_setprio(1);
#pragma unroll
            for (int mt = 0; mt < 2; mt++) {
#pragma unroll
                for (int c = 0; c < 2; c++) {
                    v8s af = *(const v8s*)(pw + (mt * 16 + col) * 72 + c * 32 + quad * 8);
#pragma unroll
                    for (int nt = 0; nt < 4; nt++)
                        acc_o[mt][nt] = __builtin_amdgcn_mfma_f32_16x16x32_bf16(af, vf[c][nt], acc_o[mt][nt], 0, 0, 0);
                }
            }
            __builtin_amdgcn_s_setprio(0);

#pragma unroll
            for (int c = 0; c < 2; c++)
#pragma unroll
                for (int nt = 0; nt < 4; nt++)
                    kc[c][nt] = kn[c][nt];
        }

        // per-wave l: reduce across quads; all lanes -> l[q=col]
#pragma unroll
        for (int mt = 0; mt < 2; mt++) {
            lpart[mt] += __shfl_xor(lpart[mt], 16);
            lpart[mt] += __shfl_xor(lpart[mt], 32);
        }

        auto store_part = [&](float* dst) {
#pragma unroll
            for (int mt = 0; mt < 2; mt++)
#pragma unroll
                for (int nt = 0; nt < 4; nt++)
                    *(v4f*)(dst + (mt * 4 + nt) * 4) = acc_o[mt][nt];
            dst[32] = lpart[0];
            dst[33] = lpart[1];
        };
        auto add_part = [&](const float* src) {
#pragma unroll
            for (int mt = 0; mt < 2; mt++)
#pragma unroll
                for (int nt = 0; nt < 4; nt++) {
                    v4f o = *(const v4f*)(src + (mt * 4 + nt) * 4);
#pragma unroll
                    for (int r = 0; r < 4; r++) acc_o[mt][nt][r] += o[r];
                }
            lpart[0] += src[32];
            lpart[1] += src[33];
        };

        // ---- 2-round combine tree (4 partials, fixed-max linear) ----
        __syncthreads();                  // pw use complete; smem -> comb
        if (wave == 1)      store_part(cb0 + lane * 34);
        else if (wave == 3) store_part(cb1 + lane * 34);
        __syncthreads();
        if (wave == 0)      add_part(cb0 + lane * 34);
        else if (wave == 2) add_part(cb1 + lane * 34);
        __syncthreads();
        if (wave == 2)      store_part(cb0 + lane * 34);
        __syncthreads();
        if (wave == 0) {
            add_part(cb0 + lane * 34);
            // normalize and write O
            float i0 = 1.0f / lpart[0];
            float i1 = 1.0f / lpart[1];
            float li[2][4];
#pragma unroll
            for (int r = 0; r < 4; r++) {
                li[0][r] = __shfl(i0, quad * 4 + r);
                li[1][r] = __shfl(i1, quad * 4 + r);
            }
#pragma unroll
            for (int mt = 0; mt < 2; mt++) {
#pragma unroll
                for (int nt = 0; nt < 4; nt++) {
#pragma unroll
                    for (int r = 0; r < 4; r++) {
                        size_t addr = ((size_t)bh * S_LEN + r0 + mt * 16 + quad * 4 + r) * DK + nt * 16 + col;
                        Op[addr] = f2bf(acc_o[mt][nt][r] * li[mt][r]);
                    }
                }
            }
        }
        __syncthreads();                  // comb reads done before pw reuse
    };

    process(63 - pr);   // heavy tile first
    process(pr);        // complementary light tile
}

// ---------------------------------------------------------------------------
// Final projection — counted-vmcnt 3-buffer pipeline (R17, unchanged).
// ---------------------------------------------------------------------------
__global__ __launch_bounds__(256) void gemm_out(
    const unsigned short* __restrict__ Ap,
    const unsigned short* __restrict__ Wot,
    const float* __restrict__ bo,
    float* __restrict__ out)
{
    __shared__ unsigned short lds_a[3][64 * 32];    // 3 x 4 KB
    __shared__ unsigned short lds_b[3][128 * 32];   // 3 x 8 KB

    const int id   = blockIdx.x;
    const int xcd  = id & 7;
    const int slot = id >> 3;
    const int nblk = slot & 7;
    const int mg   = slot >> 3;
    const int mblk = mg * 8 + xcd;   // 0..63

    const int tid  = threadIdx.x;
    const int lane = tid & 63;
    const int wave = tid >> 6;
    const int wm   = wave >> 1;
    const int wn   = wave & 1;
    const int quad = lane >> 4;
    const int col  = lane & 15;
    const int m0   = mblk * 64;
    const int n0   = nblk * 128;

    v4f acc[2][4];
#pragma unroll
    for (int i = 0; i < 2; i++)
#pragma unroll
        for (int j = 0; j < 4; j++)
#pragma unroll
            for (int r = 0; r < 4; r++) acc[i][j][r] = 0.0f;

    const int srow = wave * 16 + (lane >> 2);    // 0..63
    const int schk = (lane & 3) * 8;
    const int soff = wave * 512 + lane * 8;

    const int tokA = m0 + srow;
    const int bbA  = tokA >> 11, ttA = tokA & 2047;
    const unsigned short* Abase = Ap + ((size_t)bbA * NHEAD * S_LEN + ttA) * DK;
    const unsigned short* Wr0 = Wot + (size_t)(n0 + srow) * D_DIM + schk;
    const unsigned short* Wr1 = Wot + (size_t)(n0 + 64 + srow) * D_DIM + schk;

    auto stage = [&](unsigned short* A, unsigned short* B, int k0) {
        const int h_  = k0 >> 6;
        const int dk_ = (k0 & 63) + schk;
        gload_lds16(Abase + (size_t)h_ * S_LEN * DK + dk_, A + soff);
        gload_lds16(Wr0 + k0, B + soff);
        gload_lds16(Wr1 + k0, B + soff + 2048);
    };

    auto compute = [&](const unsigned short* A, const unsigned short* B) {
        v8s af[2], bf[4];
#pragma unroll
        for (int mt = 0; mt < 2; mt++)
            af[mt] = *(const v8s*)(A + (wm * 32 + mt * 16 + col) * 32 + quad * 8);
#pragma unroll
        for (int nt = 0; nt < 4; nt++)
            bf[nt] = *(const v8s*)(B + (wn * 64 + nt * 16 + col) * 32 + quad * 8);
#pragma unroll
        for (int mt = 0; mt < 2; mt++)
#pragma unroll
            for (int nt = 0; nt < 4; nt++)
                acc[mt][nt] = __builtin_amdgcn_mfma_f32_16x16x32_bf16(
                    af[mt], bf[nt], acc[mt][nt], 0, 0, 0);
    };

    stage(lds_a[0], lds_b[0], 0);
    stage(lds_a[1], lds_b[1], 32);

    unsigned short *ra = lds_a[0], *rb = lds_b[0];
    unsigned short *pa = lds_a[1], *pb = lds_b[1];
    unsigned short *sa = lds_a[2], *sb = lds_b[2];

    for (int k0 = 0; k0 < 992; k0 += 32) {
        asm volatile("s_waitcnt vmcnt(3)" ::: "memory");
        asm volatile("s_waitcnt lgkmcnt(0)" ::: "memory");
        __builtin_amdgcn_sched_barrier(0);
        __builtin_amdgcn_s_barrier();
        __builtin_amdgcn_sched_barrier(0);
        if (k0 + 64 < 1024) stage(sa, sb, k0 + 64);
        compute(ra, rb);
        unsigned short* t;
        t = ra; ra = pa; pa = sa; sa = t;
        t = rb; rb = pb; pb = sb; sb = t;
    }
    asm volatile("s_waitcnt vmcnt(0)" ::: "memory");
    asm volatile("s_waitcnt lgkmcnt(0)" ::: "memory");
    __builtin_amdgcn_sched_barrier(0);
    __builtin_amdgcn_s_barrier();
    __builtin_amdgcn_sched_barrier(0);
    compute(ra, rb);

    float bvv[4];
    int   nn[4];
#pragma unroll
    for (int nt = 0; nt < 4; nt++) {
        nn[nt]  = n0 + wn * 64 + nt * 16 + col;
        bvv[nt] = bo[nn[nt]];
    }

#pragma unroll
    for (int mt = 0; mt < 2; mt++) {
#pragma unroll
        for (int nt = 0; nt < 4; nt++) {
#pragma unroll
            for (int r = 0; r < 4; r++) {
                int row = m0 + wm * 32 + mt * 16 + quad * 4 + r;
                out[(size_t)row * D_DIM + nn[nt]] = acc[mt][nt][r] + bvv[nt];
            }
        }
    }
}

// ---------------------------------------------------------------------------
extern "C" void kernel_launch(void* const* d_in, const int* in_sizes, int n_in,
                              void* d_out, int out_size, void* d_ws, size_t ws_size,
                              hipStream_t stream) {
    const float* q  = (const float*)d_in[0];
    const float* k  = (const float*)d_in[1];
    const float* v  = (const float*)d_in[2];
    const float* Wq = (const float*)d_in[4];
    const float* bq = (const float*)d_in[5];
    const float* Wk = (const float*)d_in[6];
    const float* bk = (const float*)d_in[7];
    const float* Wv = (const float*)d_in[8];
    const float* bv = (const float*)d_in[9];
    const float* Wo = (const float*)d_in[10];
    const float* bo = (const float*)d_in[11];
    float* out = (float*)d_out;

    unsigned short* ws = (unsigned short*)d_ws;
    const size_t WT   = (size_t)D_DIM * D_DIM;     // 1M elems
    const size_t TENS = (size_t)M_ROWS * D_DIM;    // 4M elems
    unsigned short* Wt = ws;                        // 8 MB
    unsigned short* Qp = ws + 4 * WT;               // 8 MB
    unsigned short* Kp = Qp + TENS;                 // 8 MB
    unsigned short* Vt = Kp + TENS;                 // 8 MB
    unsigned short* Xb = Vt + TENS;                 // 24 MB (3 x 8)
    unsigned short* Ap = Xb;                        // aliases Xb[z=0] (dead after gemm_qkv)

    prep<<<7168, 256, 0, stream>>>(q, k, v, Wq, Wk, Wv, Wo, Xb, Wt);
    gemm_qkv<<<768, 256, 0, stream>>>(Xb, Wt, bq, bk, bv, Qp, Kp, Vt);
    flash11<<<1024, 256, 0, stream>>>(Qp, Kp, Vt, Ap);
    gemm_out<<<512, 256, 0, stream>>>(Ap, Wt + 3 * WT, bo, out);
}

// Round 9
// 237.103 us; speedup vs baseline: 1.1079x; 1.1079x over previous
//
#include <hip/hip_runtime.h>

// MultiHeadAttention: B=2, S=2048, D=1024, H=16, DK=64, causal.
// Inputs fp32, output fp32, intermediates bf16.
// R19: flash12 — paired-q-tile flash. R18 falsified the residency theory
//   (2x waves -> occupancy flat, time worse). New model: per-step serial
//   chain is irreducible per wave; need intra-wave ILP from independent
//   work. Each block (2 waves, flash10 schedule) owns complementary tiles
//   (63-pr, pr): light tile's KV range ⊂ heavy's, so ONE kc/vf register set
//   feeds both tiles' MFMAs (no extra loads/prologue; nsA>=17 so no empty
//   waves). Step order QKexp_A,pack_A,QKexp_B,pack_B,PV_A,PV_B: A's LDS
//   round-trip hidden under B's independent chain, B's under PV_A. Also:
//   uniform makespan (~33 steps/block) + halved K/V fetch.
// prep/gemm_qkv/gemm_out = R17 (counted-vmcnt 3-buf pipeline; 255.6us best).
// ws (56 MB, aliased): Wt 8 | Qp 8 | Kp 8 | Vt 8 | Xb 24 (Ap aliases Xb[0:8])

typedef short v8s  __attribute__((ext_vector_type(8)));
typedef short v4ss __attribute__((ext_vector_type(4)));
typedef float v4f  __attribute__((ext_vector_type(4)));
typedef unsigned int v2u __attribute__((ext_vector_type(2)));

#define S_LEN 2048
#define D_DIM 1024
#define NHEAD 16
#define DK 64
#define M_ROWS 4096

__device__ inline unsigned short f2bf(float f) {
    unsigned x;
    __builtin_memcpy(&x, &f, 4);
    unsigned r = x + 0x7fffu + ((x >> 16) & 1u);  // RNE
    return (unsigned short)(r >> 16);
}

__device__ inline unsigned cvtpk_bf16(float lo, float hi) {
    unsigned d;
    asm("v_cvt_pk_bf16_f32 %0, %1, %2" : "=v"(d) : "v"(lo), "v"(hi));
    return d;
}

__device__ inline void gload_lds16(const void* g, void* l) {
    __builtin_amdgcn_global_load_lds(
        (const __attribute__((address_space(1))) unsigned int*)g,
        (__attribute__((address_space(3))) unsigned int*)l, 16, 0, 0);
}

// ---------------------------------------------------------------------------
// prep: fp32->bf16 cvt of q,k,v into Xb (blocks 0..6143) + weight transpose
// (blocks 6144..7167). R17, unchanged.
// ---------------------------------------------------------------------------
__global__ __launch_bounds__(256) void prep(
    const float* __restrict__ q, const float* __restrict__ k,
    const float* __restrict__ v,
    const float* __restrict__ W0, const float* __restrict__ W1,
    const float* __restrict__ W2, const float* __restrict__ W3,
    unsigned short* __restrict__ Xb, unsigned short* __restrict__ Wt)
{
    __shared__ unsigned short t[64][72];
    const int id = blockIdx.x;

    if (id < 6144) {
        const int z = id >> 11;
        const int x = id & 2047;
        const float* X = (z == 0) ? q : (z == 1) ? k : v;
        const size_t off = ((size_t)x * 256 + threadIdx.x) * 8;
        float4 f0 = *(const float4*)(X + off);
        float4 f1 = *(const float4*)(X + off + 4);
        v8s p;
        p[0]=(short)f2bf(f0.x); p[1]=(short)f2bf(f0.y); p[2]=(short)f2bf(f0.z); p[3]=(short)f2bf(f0.w);
        p[4]=(short)f2bf(f1.x); p[5]=(short)f2bf(f1.y); p[6]=(short)f2bf(f1.z); p[7]=(short)f2bf(f1.w);
        *(v8s*)(Xb + (size_t)z * M_ROWS * D_DIM + off) = p;
        return;
    }

    const int tt = id - 6144;
    const int z  = tt >> 8;
    const int rem = tt & 255;
    const int bx = rem & 15;
    const int by = rem >> 4;
    const float* W = (z == 0) ? W0 : (z == 1) ? W1 : (z == 2) ? W2 : W3;
    unsigned short* dst = Wt + (size_t)z * D_DIM * D_DIM;

    const int n0 = bx * 64, k0 = by * 64;
    const int tid = threadIdx.x;
    const int lr = tid >> 4;
    const int lc = (tid & 15) * 4;

#pragma unroll
    for (int kk = 0; kk < 64; kk += 16) {
        float4 f = *(const float4*)(W + (size_t)(k0 + kk + lr) * D_DIM + n0 + lc);
        t[lc + 0][kk + lr] = f2bf(f.x);
        t[lc + 1][kk + lr] = f2bf(f.y);
        t[lc + 2][kk + lr] = f2bf(f.z);
        t[lc + 3][kk + lr] = f2bf(f.w);
    }
    __syncthreads();
    const int wr = tid >> 2;
    const int wc = (tid & 3) * 16;
    v8s o0, o1;
#pragma unroll
    for (int e = 0; e < 8; e++) { o0[e] = t[wr][wc + e]; o1[e] = t[wr][wc + 8 + e]; }
    *(v8s*)(dst + (size_t)(n0 + wr) * D_DIM + k0 + wc)     = o0;
    *(v8s*)(dst + (size_t)(n0 + wr) * D_DIM + k0 + wc + 8) = o1;
}

// ---------------------------------------------------------------------------
// Fused QKV projection — counted-vmcnt 3-buffer pipeline (R17, unchanged).
// ---------------------------------------------------------------------------
__global__ __launch_bounds__(256) void gemm_qkv(
    const unsigned short* __restrict__ Xb,
    const unsigned short* __restrict__ Wt,
    const float* __restrict__ bq, const float* __restrict__ bk,
    const float* __restrict__ bv,
    unsigned short* __restrict__ Qp, unsigned short* __restrict__ Kp,
    unsigned short* __restrict__ Vt)
{
    const int id   = blockIdx.x;
    const int xcd  = id & 7;
    const int slot = id >> 3;
    const int nblk = slot & 7;
    const int mg   = (slot >> 3) & 3;
    const int z    = slot >> 5;
    const int mblk = mg * 8 + xcd;

    const unsigned short* X = Xb + (size_t)z * M_ROWS * D_DIM;
    const unsigned short* W = Wt + (size_t)z * D_DIM * D_DIM;
    const float* bias = (z == 0) ? bq : (z == 1) ? bk : bv;

    __shared__ unsigned short lds_a[3][128 * 32];
    __shared__ unsigned short lds_b[3][128 * 32];

    const int tid  = threadIdx.x;
    const int lane = tid & 63;
    const int wave = tid >> 6;
    const int wm   = wave >> 1;
    const int wn   = wave & 1;
    const int quad = lane >> 4;
    const int col  = lane & 15;
    const int m0   = mblk * 128;
    const int n0   = nblk * 128;

    v4f acc[4][4];
#pragma unroll
    for (int i = 0; i < 4; i++)
#pragma unroll
        for (int j = 0; j < 4; j++)
#pragma unroll
            for (int r = 0; r < 4; r++) acc[i][j][r] = 0.0f;

    const int srow = wave * 16 + (lane >> 2);
    const int schk = (lane & 3) * 8;
    const int soff = wave * 512 + lane * 8;

    const unsigned short* Xr0 = X + (size_t)(m0 + srow) * D_DIM + schk;
    const unsigned short* Xr1 = X + (size_t)(m0 + 64 + srow) * D_DIM + schk;
    const unsigned short* Wr0 = W + (size_t)(n0 + srow) * D_DIM + schk;
    const unsigned short* Wr1 = W + (size_t)(n0 + 64 + srow) * D_DIM + schk;

    auto stage = [&](unsigned short* A, unsigned short* B, int k0) {
        gload_lds16(Xr0 + k0, A + soff);
        gload_lds16(Xr1 + k0, A + soff + 2048);
        gload_lds16(Wr0 + k0, B + soff);
        gload_lds16(Wr1 + k0, B + soff + 2048);
    };

    auto compute = [&](const unsigned short* A, const unsigned short* B) {
        v8s af[4], bf[4];
#pragma unroll
        for (int mt = 0; mt < 4; mt++)
            af[mt] = *(const v8s*)(A + (wm * 64 + mt * 16 + col) * 32 + quad * 8);
#pragma unroll
        for (int nt = 0; nt < 4; nt++)
            bf[nt] = *(const v8s*)(B + (wn * 64 + nt * 16 + col) * 32 + quad * 8);
#pragma unroll
        for (int mt = 0; mt < 4; mt++)
#pragma unroll
            for (int nt = 0; nt < 4; nt++)
                acc[mt][nt] = __builtin_amdgcn_mfma_f32_16x16x32_bf16(
                    af[mt], bf[nt], acc[mt][nt], 0, 0, 0);
    };

    stage(lds_a[0], lds_b[0], 0);
    stage(lds_a[1], lds_b[1], 32);

    unsigned short *ra = lds_a[0], *rb = lds_b[0];
    unsigned short *pa = lds_a[1], *pb = lds_b[1];
    unsigned short *sa = lds_a[2], *sb = lds_b[2];

    for (int k0 = 0; k0 < 992; k0 += 32) {
        asm volatile("s_waitcnt vmcnt(4)" ::: "memory");
        asm volatile("s_waitcnt lgkmcnt(0)" ::: "memory");
        __builtin_amdgcn_sched_barrier(0);
        __builtin_amdgcn_s_barrier();
        __builtin_amdgcn_sched_barrier(0);
        if (k0 + 64 < 1024) stage(sa, sb, k0 + 64);
        compute(ra, rb);
        unsigned short* t;
        t = ra; ra = pa; pa = sa; sa = t;
        t = rb; rb = pb; pb = sb; sb = t;
    }
    asm volatile("s_waitcnt vmcnt(0)" ::: "memory");
    asm volatile("s_waitcnt lgkmcnt(0)" ::: "memory");
    __builtin_amdgcn_sched_barrier(0);
    __builtin_amdgcn_s_barrier();
    __builtin_amdgcn_sched_barrier(0);
    compute(ra, rb);

    int   nn[4];
    float bvv[4];
#pragma unroll
    for (int nt = 0; nt < 4; nt++) {
        nn[nt]  = n0 + wn * 64 + nt * 16 + col;
        bvv[nt] = bias[nn[nt]];
    }

    if (z < 2) {
        unsigned short* out = (z == 0) ? Qp : Kp;
#pragma unroll
        for (int mt = 0; mt < 4; mt++) {
#pragma unroll
            for (int nt = 0; nt < 4; nt++) {
                const int h  = nn[nt] >> 6;
                const int dk = nn[nt] & 63;
#pragma unroll
                for (int r = 0; r < 4; r++) {
                    int row = m0 + wm * 64 + mt * 16 + quad * 4 + r;
                    int b   = row >> 11, t = row & 2047;
                    out[(((size_t)(b * NHEAD + h) * S_LEN) + t) * DK + dk] =
                        f2bf(acc[mt][nt][r] + bvv[nt]);
                }
            }
        }
    } else {
#pragma unroll
        for (int mt = 0; mt < 4; mt++) {
#pragma unroll
            for (int nt = 0; nt < 4; nt++) {
                const int h  = nn[nt] >> 6;
                const int dk = nn[nt] & 63;
                int row = m0 + wm * 64 + mt * 16 + quad * 4;
                int b   = row >> 11, t = row & 2047;
                v4ss pk;
#pragma unroll
                for (int r = 0; r < 4; r++) pk[r] = (short)f2bf(acc[mt][nt][r] + bvv[nt]);
                *(v4ss*)(Vt + ((size_t)(b * NHEAD + h) * DK + dk) * S_LEN + t) = pk;
            }
        }
    }
}

// ---------------------------------------------------------------------------
// Flash attention v12 — paired q-tiles per block, shared K/V registers.
// 1024 blocks x 128 thr (2 waves, even/odd steps). Block owns bh and pair
// (q32a=63-pr, q32b=pr); light's KV steps ⊂ heavy's, same kc/vf feed both.
// Step: QKexp_A, pack_A, QKexp_B, pack_B, PV_A, PV_B (independent chains
// cover each other's LDS round-trips). Fixed-CM deferred softmax; 1-round
// combine carrying both tiles' partials.
// ---------------------------------------------------------------------------
__global__ __launch_bounds__(128) void flash12(
    const unsigned short* __restrict__ Qp,
    const unsigned short* __restrict__ Kp,
    const unsigned short* __restrict__ Vt,
    unsigned short* __restrict__ Op)
{
    // pw: 2 waves x 2 tiles x [32][72] shorts = 18432 B | comb 64x68 f32 = 17408 B
    __shared__ __align__(16) unsigned char smem[18432];

    const int tid  = threadIdx.x;
    const int wave = tid >> 6;
    const int lane = tid & 63;
    const int quad = lane >> 4;
    const int col  = lane & 15;

    unsigned short* pwA = (unsigned short*)smem + wave * 2 * (32 * 72);
    unsigned short* pwB = pwA + 32 * 72;

    const int i   = blockIdx.x;
    const int xcd = i & 7;
    const int j   = i >> 3;            // 0..127
    const int bh  = xcd * 4 + (j & 3);
    const int pr  = j >> 2;            // 0..31
    const int q32a = 63 - pr, q32b = pr;
    const int r0a = q32a * 32, r0b = q32b * 32;
    const int nsA = (q32a >> 1) + 1;   // >= 17
    const int nsB = (q32b >> 1) + 1;   // <= 16 <= nsA

    const unsigned short* Qh = Qp + (size_t)bh * S_LEN * DK;
    const unsigned short* Kh = Kp + (size_t)bh * S_LEN * DK;
    const unsigned short* Vh = Vt + (size_t)bh * DK * S_LEN;

    v8s qfa[2][2], qfb[2][2];
#pragma unroll
    for (int mt = 0; mt < 2; mt++)
#pragma unroll
        for (int c = 0; c < 2; c++) {
            qfa[mt][c] = *(const v8s*)(Qh + (size_t)(r0a + mt * 16 + col) * DK + c * 32 + quad * 8);
            qfb[mt][c] = *(const v8s*)(Qh + (size_t)(r0b + mt * 16 + col) * DK + c * 32 + quad * 8);
        }

    float lpa[2] = {0.f, 0.f}, lpb[2] = {0.f, 0.f};
    v4f acca[2][4], accb[2][4];
#pragma unroll
    for (int mt = 0; mt < 2; mt++)
#pragma unroll
        for (int nt = 0; nt < 4; nt++)
#pragma unroll
            for (int r = 0; r < 4; r++) { acca[mt][nt][r] = 0.0f; accb[mt][nt][r] = 0.0f; }

    const float CS = 0.18033688f;   // 0.125*log2(e)
    const float CM = 28.8539008f;   // 20*log2(e)

    v8s kc[2][4];
    const int kvp = wave * 64;
#pragma unroll
    for (int c = 0; c < 2; c++)
#pragma unroll
        for (int nt = 0; nt < 4; nt++)
            kc[c][nt] = *(const v8s*)(Kh + (size_t)(kvp + nt * 16 + col) * DK + c * 32 + quad * 8);

    for (int step = wave; step < nsA; step += 2) {
        const int kv0 = step * 64;
        const int kvn = (step + 2 < nsA) ? kv0 + 128 : kv0;
        const bool doB = (step < nsB);

        v8s vf[2][4];
#pragma unroll
        for (int c = 0; c < 2; c++)
#pragma unroll
            for (int nt = 0; nt < 4; nt++)
                vf[c][nt] = *(const v8s*)(Vh + (size_t)(nt * 16 + col) * S_LEN + kv0 + c * 32 + quad * 8);
        v8s kn[2][4];
#pragma unroll
        for (int c = 0; c < 2; c++)
#pragma unroll
            for (int nt = 0; nt < 4; nt++)
                kn[c][nt] = *(const v8s*)(Kh + (size_t)(kvn + nt * 16 + col) * DK + c * 32 + quad * 8);

        // ---- tile A: QK + exp + pack (swapped operands: q=col, kv=nt*16+quad*4+r)
#pragma unroll
        for (int mt = 0; mt < 2; mt++) {
            v4f s[4];
            __builtin_amdgcn_s_setprio(1);
#pragma unroll
            for (int nt = 0; nt < 4; nt++) {
#pragma unroll
                for (int r = 0; r < 4; r++) s[nt][r] = 0.0f;
#pragma unroll
                for (int c = 0; c < 2; c++)
                    s[nt] = __builtin_amdgcn_mfma_f32_16x16x32_bf16(kc[c][nt], qfa[mt][c], s[nt], 0, 0, 0);
            }
            __builtin_amdgcn_s_setprio(0);

            const int rbase = r0a + mt * 16;
            float lp = 0.f;
            if (kv0 + 64 > rbase) {
#pragma unroll
                for (int nt = 0; nt < 4; nt++)
#pragma unroll
                    for (int r = 0; r < 4; r++) {
                        float p = __builtin_amdgcn_exp2f(fmaf(s[nt][r], CS, -CM));
                        if (kv0 + nt * 16 + quad * 4 + r > rbase + col) p = 0.0f;
                        s[nt][r] = p;
                        lp += p;
                    }
            } else {
#pragma unroll
                for (int nt = 0; nt < 4; nt++)
#pragma unroll
                    for (int r = 0; r < 4; r++) {
                        float p = __builtin_amdgcn_exp2f(fmaf(s[nt][r], CS, -CM));
                        s[nt][r] = p;
                        lp += p;
                    }
            }
            lpa[mt] += lp;

#pragma unroll
            for (int nt = 0; nt < 4; nt++) {
                unsigned u0 = cvtpk_bf16(s[nt][0], s[nt][1]);
                unsigned u1 = cvtpk_bf16(s[nt][2], s[nt][3]);
                v2u w; w[0] = u0; w[1] = u1;
                *(v2u*)(pwA + (mt * 16 + col) * 72 + nt * 16 + quad * 4) = w;
            }
        }

        // ---- tile B: QK + exp + pack (independent of A; covers A's LDS latency)
        if (doB) {
#pragma unroll
            for (int mt = 0; mt < 2; mt++) {
                v4f s[4];
                __builtin_amdgcn_s_setprio(1);
#pragma unroll
                for (int nt = 0; nt < 4; nt++) {
#pragma unroll
                    for (int r = 0; r < 4; r++) s[nt][r] = 0.0f;
#pragma unroll
                    for (int c = 0; c < 2; c++)
                        s[nt] = __builtin_amdgcn_mfma_f32_16x16x32_bf16(kc[c][nt], qfb[mt][c], s[nt], 0, 0, 0);
                }
                __builtin_amdgcn_s_setprio(0);

                const int rbase = r0b + mt * 16;
                float lp = 0.f;
                if (kv0 + 64 > rbase) {
#pragma unroll
                    for (int nt = 0; nt < 4; nt++)
#pragma unroll
                        for (int r = 0; r < 4; r++) {
                            float p = __builtin_amdgcn_exp2f(fmaf(s[nt][r], CS, -CM));
                            if (kv0 + nt * 16 + quad * 4 + r > rbase + col) p = 0.0f;
                            s[nt][r] = p;
                            lp += p;
                        }
                } else {
#pragma unroll
                    for (int nt = 0; nt < 4; nt++)
#pragma unroll
                        for (int r = 0; r < 4; r++) {
                            float p = __builtin_amdgcn_exp2f(fmaf(s[nt][r], CS, -CM));
                            s[nt][r] = p;
                            lp += p;
                        }
                }
                lpb[mt] += lp;

#pragma unroll
                for (int nt = 0; nt < 4; nt++) {
                    unsigned u0 = cvtpk_bf16(s[nt][0], s[nt][1]);
                    unsigned u1 = cvtpk_bf16(s[nt][2], s[nt][3]);
                    v2u w; w[0] = u0; w[1] = u1;
                    *(v2u*)(pwB + (mt * 16 + col) * 72 + nt * 16 + quad * 4) = w;
                }
            }
        }

        // ---- PV A then PV B (A's reads long-separated from A's writes)
        __builtin_amdgcn_s_setprio(1);
#pragma unroll
        for (int mt = 0; mt < 2; mt++)
#pragma unroll
            for (int c = 0; c < 2; c++) {
                v8s af = *(const v8s*)(pwA + (mt * 16 + col) * 72 + c * 32 + quad * 8);
#pragma unroll
                for (int nt = 0; nt < 4; nt++)
                    acca[mt][nt] = __builtin_amdgcn_mfma_f32_16x16x32_bf16(af, vf[c][nt], acca[mt][nt], 0, 0, 0);
            }
        if (doB) {
#pragma unroll
            for (int mt = 0; mt < 2; mt++)
#pragma unroll
                for (int c = 0; c < 2; c++) {
                    v8s af = *(const v8s*)(pwB + (mt * 16 + col) * 72 + c * 32 + quad * 8);
#pragma unroll
                    for (int nt = 0; nt < 4; nt++)
                        accb[mt][nt] = __builtin_amdgcn_mfma_f32_16x16x32_bf16(af, vf[c][nt], accb[mt][nt], 0, 0, 0);
                }
        }
        __builtin_amdgcn_s_setprio(0);

#pragma unroll
        for (int c = 0; c < 2; c++)
#pragma unroll
            for (int nt = 0; nt < 4; nt++)
                kc[c][nt] = kn[c][nt];
    }

    // per-wave l: reduce across quads; all lanes -> l[q=col]
#pragma unroll
    for (int mt = 0; mt < 2; mt++) {
        lpa[mt] += __shfl_xor(lpa[mt], 16);
        lpa[mt] += __shfl_xor(lpa[mt], 32);
        lpb[mt] += __shfl_xor(lpb[mt], 16);
        lpb[mt] += __shfl_xor(lpb[mt], 32);
    }

    // ---- cross-wave combine (both tiles; fixed-max linear) ----
    float* comb = (float*)smem;
    __syncthreads();                      // pw use complete; smem reusable
    if (wave == 1) {
        float* dst = comb + lane * 68;
#pragma unroll
        for (int mt = 0; mt < 2; mt++)
#pragma unroll
            for (int nt = 0; nt < 4; nt++) {
                *(v4f*)(dst + (mt * 4 + nt) * 4)      = acca[mt][nt];
                *(v4f*)(dst + 34 + (mt * 4 + nt) * 4) = accb[mt][nt];
            }
        dst[32] = lpa[0]; dst[33] = lpa[1];
        dst[66] = lpb[0]; dst[67] = lpb[1];
    }
    __syncthreads();
    if (wave != 0) return;

    {
        const float* src = comb + lane * 68;
#pragma unroll
        for (int mt = 0; mt < 2; mt++)
#pragma unroll
            for (int nt = 0; nt < 4; nt++) {
                v4f oa = *(const v4f*)(src + (mt * 4 + nt) * 4);
                v4f ob = *(const v4f*)(src + 34 + (mt * 4 + nt) * 4);
#pragma unroll
                for (int r = 0; r < 4; r++) { acca[mt][nt][r] += oa[r]; accb[mt][nt][r] += ob[r]; }
            }
        lpa[0] += src[32]; lpa[1] += src[33];
        lpb[0] += src[66]; lpb[1] += src[67];
    }

    // normalize + write both tiles
    lpa[0] = 1.0f / lpa[0];  lpa[1] = 1.0f / lpa[1];
    lpb[0] = 1.0f / lpb[0];  lpb[1] = 1.0f / lpb[1];
    float lia[2][4], lib[2][4];
#pragma unroll
    for (int mt = 0; mt < 2; mt++)
#pragma unroll
        for (int r = 0; r < 4; r++) {
            lia[mt][r] = __shfl(lpa[mt], quad * 4 + r);
            lib[mt][r] = __shfl(lpb[mt], quad * 4 + r);
        }

#pragma unroll
    for (int mt = 0; mt < 2; mt++) {
#pragma unroll
        for (int nt = 0; nt < 4; nt++) {
#pragma unroll
            for (int r = 0; r < 4; r++) {
                size_t aA = ((size_t)bh * S_LEN + r0a + mt * 16 + quad * 4 + r) * DK + nt * 16 + col;
                Op[aA] = f2bf(acca[mt][nt][r] * lia[mt][r]);
                size_t aB = ((size_t)bh * S_LEN + r0b + mt * 16 + quad * 4 + r) * DK + nt * 16 + col;
                Op[aB] = f2bf(accb[mt][nt][r] * lib[mt][r]);
            }
        }
    }
}

// ---------------------------------------------------------------------------
// Final projection — counted-vmcnt 3-buffer pipeline (R17, unchanged).
// ---------------------------------------------------------------------------
__global__ __launch_bounds__(256) void gemm_out(
    const unsigned short* __restrict__ Ap,
    const unsigned short* __restrict__ Wot,
    const float* __restrict__ bo,
    float* __restrict__ out)
{
    __shared__ unsigned short lds_a[3][64 * 32];
    __shared__ unsigned short lds_b[3][128 * 32];

    const int id   = blockIdx.x;
    const int xcd  = id & 7;
    const int slot = id >> 3;
    const int nblk = slot & 7;
    const int mg   = slot >> 3;
    const int mblk = mg * 8 + xcd;

    const int tid  = threadIdx.x;
    const int lane = tid & 63;
    const int wave = tid >> 6;
    const int wm   = wave >> 1;
    const int wn   = wave & 1;
    const int quad = lane >> 4;
    const int col  = lane & 15;
    const int m0   = mblk * 64;
    const int n0   = nblk * 128;

    v4f acc[2][4];
#pragma unroll
    for (int i = 0; i < 2; i++)
#pragma unroll
        for (int j = 0; j < 4; j++)
#pragma unroll
            for (int r = 0; r < 4; r++) acc[i][j][r] = 0.0f;

    const int srow = wave * 16 + (lane >> 2);
    const int schk = (lane & 3) * 8;
    const int soff = wave * 512 + lane * 8;

    const int tokA = m0 + srow;
    const int bbA  = tokA >> 11, ttA = tokA & 2047;
    const unsigned short* Abase = Ap + ((size_t)bbA * NHEAD * S_LEN + ttA) * DK;
    const unsigned short* Wr0 = Wot + (size_t)(n0 + srow) * D_DIM + schk;
    const unsigned short* Wr1 = Wot + (size_t)(n0 + 64 + srow) * D_DIM + schk;

    auto stage = [&](unsigned short* A, unsigned short* B, int k0) {
        const int h_  = k0 >> 6;
        const int dk_ = (k0 & 63) + schk;
        gload_lds16(Abase + (size_t)h_ * S_LEN * DK + dk_, A + soff);
        gload_lds16(Wr0 + k0, B + soff);
        gload_lds16(Wr1 + k0, B + soff + 2048);
    };

    auto compute = [&](const unsigned short* A, const unsigned short* B) {
        v8s af[2], bf[4];
#pragma unroll
        for (int mt = 0; mt < 2; mt++)
            af[mt] = *(const v8s*)(A + (wm * 32 + mt * 16 + col) * 32 + quad * 8);
#pragma unroll
        for (int nt = 0; nt < 4; nt++)
            bf[nt] = *(const v8s*)(B + (wn * 64 + nt * 16 + col) * 32 + quad * 8);
#pragma unroll
        for (int mt = 0; mt < 2; mt++)
#pragma unroll
            for (int nt = 0; nt < 4; nt++)
                acc[mt][nt] = __builtin_amdgcn_mfma_f32_16x16x32_bf16(
                    af[mt], bf[nt], acc[mt][nt], 0, 0, 0);
    };

    stage(lds_a[0], lds_b[0], 0);
    stage(lds_a[1], lds_b[1], 32);

    unsigned short *ra = lds_a[0], *rb = lds_b[0];
    unsigned short *pa = lds_a[1], *pb = lds_b[1];
    unsigned short *sa = lds_a[2], *sb = lds_b[2];

    for (int k0 = 0; k0 < 992; k0 += 32) {
        asm volatile("s_waitcnt vmcnt(3)" ::: "memory");
        asm volatile("s_waitcnt lgkmcnt(0)" ::: "memory");
        __builtin_amdgcn_sched_barrier(0);
        __builtin_amdgcn_s_barrier();
        __builtin_amdgcn_sched_barrier(0);
        if (k0 + 64 < 1024) stage(sa, sb, k0 + 64);
        compute(ra, rb);
        unsigned short* t;
        t = ra; ra = pa; pa = sa; sa = t;
        t = rb; rb = pb; pb = sb; sb = t;
    }
    asm volatile("s_waitcnt vmcnt(0)" ::: "memory");
    asm volatile("s_waitcnt lgkmcnt(0)" ::: "memory");
    __builtin_amdgcn_sched_barrier(0);
    __builtin_amdgcn_s_barrier();
    __builtin_amdgcn_sched_barrier(0);
    compute(ra, rb);

    float bvv[4];
    int   nn[4];
#pragma unroll
    for (int nt = 0; nt < 4; nt++) {
        nn[nt]  = n0 + wn * 64 + nt * 16 + col;
        bvv[nt] = bo[nn[nt]];
    }

#pragma unroll
    for (int mt = 0; mt < 2; mt++) {
#pragma unroll
        for (int nt = 0; nt < 4; nt++) {
#pragma unroll
            for (int r = 0; r < 4; r++) {
                int row = m0 + wm * 32 + mt * 16 + quad * 4 + r;
                out[(size_t)row * D_DIM + nn[nt]] = acc[mt][nt][r] + bvv[nt];
            }
        }
    }
}

// ---------------------------------------------------------------------------
extern "C" void kernel_launch(void* const* d_in, const int* in_sizes, int n_in,
                              void* d_out, int out_size, void* d_ws, size_t ws_size,
                              hipStream_t stream) {
    const float* q  = (const float*)d_in[0];
    const float* k  = (const float*)d_in[1];
    const float* v  = (const float*)d_in[2];
    const float* Wq = (const float*)d_in[4];
    const float* bq = (const float*)d_in[5];
    const float* Wk = (const float*)d_in[6];
    const float* bk = (const float*)d_in[7];
    const float* Wv = (const float*)d_in[8];
    const float* bv = (const float*)d_in[9];
    const float* Wo = (const float*)d_in[10];
    const float* bo = (const float*)d_in[11];
    float* out = (float*)d_out;

    unsigned short* ws = (unsigned short*)d_ws;
    const size_t WT   = (size_t)D_DIM * D_DIM;     // 1M elems
    const size_t TENS = (size_t)M_ROWS * D_DIM;    // 4M elems
    unsigned short* Wt = ws;                        // 8 MB
    unsigned short* Qp = ws + 4 * WT;               // 8 MB
    unsigned short* Kp = Qp + TENS;                 // 8 MB
    unsigned short* Vt = Kp + TENS;                 // 8 MB
    unsigned short* Xb = Vt + TENS;                 // 24 MB (3 x 8)
    unsigned short* Ap = Xb;                        // aliases Xb[z=0] (dead after gemm_qkv)

    prep<<<7168, 256, 0, stream>>>(q, k, v, Wq, Wk, Wv, Wo, Xb, Wt);
    gemm_qkv<<<768, 256, 0, stream>>>(Xb, Wt, bq, bk, bv, Qp, Kp, Vt);
    flash12<<<1024, 128, 0, stream>>>(Qp, Kp, Vt, Ap);
    gemm_out<<<512, 256, 0, stream>>>(Ap, Wt + 3 * WT, bo, out);
}